// Round 1
// baseline (2643.134 us; speedup 1.0000x reference)
//
#include <hip/hip_runtime.h>
#include <math.h>

#define NSEQ 1024
#define DIN_ 1024
#define DQKV 2560

// ---------------- pe_proj: pe(1024x32) @ W_pos[1024:1056,:] -> (1024,1024)
__global__ __launch_bounds__(256) void pe_proj_kernel(const float* __restrict__ pe,
                                                      const float* __restrict__ W_pos,
                                                      float* __restrict__ out) {
  int idx = blockIdx.x * 256 + threadIdx.x;   // over 1024*1024
  int n = idx >> 10, c = idx & 1023;
  float s = 0.f;
#pragma unroll
  for (int e = 0; e < 32; ++e)
    s += pe[n * 32 + e] * W_pos[(size_t)(1024 + e) * 1024 + c];
  out[idx] = s;
}

// ---------------- generic fp32 GEMM: C[M,N] = A[M,K]@B[K,N] (+bias +add_full +add_mod)
// 64x64 tile, 256 threads, 4x4 microtile, K-step 16.
__global__ __launch_bounds__(256) void gemm_tiled(
    const float* __restrict__ A, const float* __restrict__ B, float* __restrict__ C,
    int M, int N, int K,
    const float* __restrict__ bias,       // [N] or null
    const float* __restrict__ add_full,   // [M,N] or null
    const float* __restrict__ add_mod) {  // [(m&1023),N] or null
  __shared__ __align__(16) float As[16][68];
  __shared__ __align__(16) float Bs[16][68];
  const int tid = threadIdx.x;
  const int tx = tid & 15, ty = tid >> 4;
  const int row0 = blockIdx.y * 64, col0 = blockIdx.x * 64;
  float acc[4][4] = {};
  for (int kt = 0; kt < K; kt += 16) {
    {  // A tile: 64 rows x 16 k, transposed into As[k][row]
      int i = tid >> 2, k4 = (tid & 3) << 2;
      float4 va = *(const float4*)&A[(size_t)(row0 + i) * K + kt + k4];
      As[k4 + 0][i] = va.x; As[k4 + 1][i] = va.y;
      As[k4 + 2][i] = va.z; As[k4 + 3][i] = va.w;
    }
    {  // B tile: 16 k x 64 cols
      int kk = tid >> 4, j = (tid & 15) << 2;
      *(float4*)&Bs[kk][j] = *(const float4*)&B[(size_t)(kt + kk) * N + col0 + j];
    }
    __syncthreads();
#pragma unroll
    for (int kk = 0; kk < 16; ++kk) {
      float4 a = *(const float4*)&As[kk][ty << 2];
      float4 b = *(const float4*)&Bs[kk][tx << 2];
      float av[4] = {a.x, a.y, a.z, a.w}, bv[4] = {b.x, b.y, b.z, b.w};
#pragma unroll
      for (int r = 0; r < 4; ++r)
#pragma unroll
        for (int c = 0; c < 4; ++c) acc[r][c] = fmaf(av[r], bv[c], acc[r][c]);
    }
    __syncthreads();
  }
#pragma unroll
  for (int r = 0; r < 4; ++r) {
    int m = row0 + (ty << 2) + r;
#pragma unroll
    for (int c = 0; c < 4; ++c) {
      int n = col0 + (tx << 2) + c;
      float v = acc[r][c];
      if (bias) v += bias[n];
      if (add_full) v += add_full[(size_t)m * N + n];
      if (add_mod) v += add_mod[(size_t)(m & 1023) * N + n];
      C[(size_t)m * N + n] = v;
    }
  }
}

// ---------------- FeatureNorm over sequence dim (axis=1), biased var, in-place.
// grid = B * (DIN/64), block = 512 (64 cols x 8 n-groups of 128)
__global__ __launch_bounds__(512) void featnorm_kernel(float* __restrict__ h,
                                                       const float* __restrict__ gamma,
                                                       const float* __restrict__ beta) {
  const int b = blockIdx.x >> 4;
  const int d0 = (blockIdx.x & 15) << 6;
  const int tid = threadIdx.x;
  const int c = tid & 63, g = tid >> 6;
  const size_t base = (size_t)b * (NSEQ * DIN_) + d0 + c;
  float s = 0.f, s2 = 0.f;
  for (int n = g * 128; n < g * 128 + 128; ++n) {
    float v = h[base + (size_t)n * DIN_];
    s += v; s2 += v * v;
  }
  __shared__ float rs[8][64], rs2[8][64];
  rs[g][c] = s; rs2[g][c] = s2;
  __syncthreads();
  __shared__ float smean[64], srstd[64];
  if (tid < 64) {
    float S = 0.f, S2 = 0.f;
#pragma unroll
    for (int q = 0; q < 8; ++q) { S += rs[q][tid]; S2 += rs2[q][tid]; }
    float mean = S * (1.f / 1024.f);
    float var = S2 * (1.f / 1024.f) - mean * mean;
    smean[tid] = mean;
    srstd[tid] = rsqrtf(var + 1e-5f);
  }
  __syncthreads();
  const float mean = smean[c], rstd = srstd[c];
  const float gm = gamma[d0 + c], bt = beta[d0 + c];
  for (int n = g * 128; n < g * 128 + 128; ++n) {
    size_t idx = base + (size_t)n * DIN_;
    h[idx] = gm * (h[idx] - mean) * rstd + bt;
  }
}

// ---------------- squared norms of q and k rows. grid = B*H*N, block = 128.
__global__ __launch_bounds__(128) void sqsk_kernel(const float* __restrict__ qkv,
                                                   float* __restrict__ sqb,
                                                   float* __restrict__ skb) {
  const int bid = blockIdx.x;              // (b*8+h)*1024 + n
  const int n = bid & 1023, bh = bid >> 10;
  const int b = bh >> 3, hh = bh & 7;
  const int tid = threadIdx.x;
  const int grp = tid >> 6, lane = tid & 63;
  size_t basep = (size_t)(b * NSEQ + n) * DQKV + (grp ? 1024 : 0) + hh * 128;
  float v0 = qkv[basep + lane], v1 = qkv[basep + 64 + lane];
  float s = v0 * v0 + v1 * v1;
#pragma unroll
  for (int off = 32; off; off >>= 1) s += __shfl_down(s, off);
  if (lane == 0) { if (grp) skb[bid] = s; else sqb[bid] = s; }
}

// ---------------- flash-style distance attention.
// grid = B*H*(N/16) = 4096 blocks, 256 threads (16 rows x 16 lanes, 4 cols/lane)
__global__ __launch_bounds__(256) void attn_kernel(const float* __restrict__ qkv,
                                                   const float* __restrict__ sqb,
                                                   const float* __restrict__ skb,
                                                   const float* __restrict__ scale_ptr,
                                                   float* __restrict__ out) {
  const int bid = blockIdx.x;
  const int it = bid & 63, bh = bid >> 6;
  const int b = bh >> 3, hh = bh & 7;
  const int i0 = it << 4;
  const int tid = threadIdx.x;
  const int tx = tid & 15, ty = tid >> 4;
  const float sc = scale_ptr[0];
  const float invs2 = 1.f / (sc * sc);
  __shared__ __align__(16) float Qs[16][132];
  __shared__ __align__(16) float Ks[64][132];
  __shared__ __align__(16) float Vs[64][64];
  __shared__ float Ps[16][68];
  for (int l = tid; l < 16 * 128; l += 256) {
    int i = l >> 7, d = l & 127;
    Qs[i][d] = qkv[(size_t)(b * NSEQ + i0 + i) * DQKV + hh * 128 + d];
  }
  const float sq_i = sqb[bh * 1024 + i0 + ty];
  float m = -1e30f, lsum = 0.f;
  float o0 = 0.f, o1 = 0.f, o2 = 0.f, o3 = 0.f;
  for (int jt = 0; jt < 16; ++jt) {
    __syncthreads();
    for (int l = tid; l < 64 * 128; l += 256) {
      int j = l >> 7, d = l & 127;
      Ks[j][d] = qkv[(size_t)(b * NSEQ + (jt << 6) + j) * DQKV + 1024 + hh * 128 + d];
    }
    for (int l = tid; l < 64 * 64; l += 256) {
      int j = l >> 6, d = l & 63;
      Vs[j][d] = qkv[(size_t)(b * NSEQ + (jt << 6) + j) * DQKV + 2048 + hh * 64 + d];
    }
    __syncthreads();
    float dot[4] = {0.f, 0.f, 0.f, 0.f};
#pragma unroll 8
    for (int d4 = 0; d4 < 32; ++d4) {
      float4 qa = *(const float4*)&Qs[ty][d4 << 2];
#pragma unroll
      for (int jj = 0; jj < 4; ++jj) {
        float4 kb = *(const float4*)&Ks[(tx << 2) + jj][d4 << 2];
        dot[jj] += qa.x * kb.x + qa.y * kb.y + qa.z * kb.z + qa.w * kb.w;
      }
    }
    float s[4];
#pragma unroll
    for (int jj = 0; jj < 4; ++jj) {
      float d2 = sq_i + skb[bh * 1024 + (jt << 6) + (tx << 2) + jj] - 2.f * dot[jj];
      d2 = fmaxf(d2, 0.f);
      s[jj] = -d2 * invs2;
    }
    float tm = fmaxf(fmaxf(s[0], s[1]), fmaxf(s[2], s[3]));
#pragma unroll
    for (int off = 8; off; off >>= 1) tm = fmaxf(tm, __shfl_xor(tm, off, 16));
    const float mn = fmaxf(m, tm);
    const float corr = __expf(m - mn);
    float p[4], ps = 0.f;
#pragma unroll
    for (int jj = 0; jj < 4; ++jj) { p[jj] = __expf(s[jj] - mn); ps += p[jj]; }
#pragma unroll
    for (int off = 8; off; off >>= 1) ps += __shfl_xor(ps, off, 16);
    lsum = lsum * corr + ps;
    m = mn;
    o0 *= corr; o1 *= corr; o2 *= corr; o3 *= corr;
#pragma unroll
    for (int jj = 0; jj < 4; ++jj) Ps[ty][(tx << 2) + jj] = p[jj];
    __syncthreads();
    for (int j = 0; j < 64; ++j) {
      float pv = Ps[ty][j];
      float4 vv = *(const float4*)&Vs[j][tx << 2];
      o0 = fmaf(pv, vv.x, o0); o1 = fmaf(pv, vv.y, o1);
      o2 = fmaf(pv, vv.z, o2); o3 = fmaf(pv, vv.w, o3);
    }
  }
  const float inv_l = 1.f / lsum;
  float4 res = make_float4(o0 * inv_l, o1 * inv_l, o2 * inv_l, o3 * inv_l);
  *(float4*)&out[(size_t)(b * NSEQ + i0 + ty) * 512 + hh * 64 + (tx << 2)] = res;
}

extern "C" void kernel_launch(void* const* d_in, const int* in_sizes, int n_in,
                              void* d_out, int out_size, void* d_ws, size_t ws_size,
                              hipStream_t stream) {
  const float* x     = (const float*)d_in[0];
  const float* gamma = (const float*)d_in[1];
  const float* beta  = (const float*)d_in[2];
  const float* pe    = (const float*)d_in[3];
  const float* W_pos = (const float*)d_in[4];
  const float* b_pos = (const float*)d_in[5];
  const float* W_qkv = (const float*)d_in[6];
  const float* b_qkv = (const float*)d_in[7];
  const float* W_out = (const float*)d_in[8];
  const float* b_out = (const float*)d_in[9];
  const float* scale = (const float*)d_in[10];
  float* outp = (float*)d_out;

  float* ws = (float*)d_ws;
  float* pe_proj = ws;                                  // 1M floats
  float* h       = pe_proj + (1 << 20);                 // 8M floats
  float* qkv     = h + (8 << 20);                       // 8192*2560 floats
  float* attn_o  = qkv + (size_t)8192 * 2560;           // 4M floats
  float* sqb     = attn_o + (4 << 20);                  // 64K floats
  float* skb     = sqb + 65536;                         // 64K floats

  // 1) pe_proj = pe @ W_pos[1024:1056]
  pe_proj_kernel<<<4096, 256, 0, stream>>>(pe, W_pos, pe_proj);
  // 2) h = x + x@W_pos[:1024] + pe_proj + b_pos
  gemm_tiled<<<dim3(1024 / 64, 8192 / 64), 256, 0, stream>>>(
      x, W_pos, h, 8192, 1024, 1024, b_pos, x, pe_proj);
  // 3) FeatureNorm over sequence dim, in place
  featnorm_kernel<<<128, 512, 0, stream>>>(h, gamma, beta);
  // 4) qkv = hn @ W_qkv + b_qkv
  gemm_tiled<<<dim3(2560 / 64, 8192 / 64), 256, 0, stream>>>(
      h, W_qkv, qkv, 8192, 2560, 1024, b_qkv, nullptr, nullptr);
  // 5) row squared-norms of q and k
  sqsk_kernel<<<65536, 128, 0, stream>>>(qkv, sqb, skb);
  // 6) attention
  attn_kernel<<<4096, 256, 0, stream>>>(qkv, sqb, skb, scale, attn_o);
  // 7) out = x + attn_o @ W_out + b_out
  gemm_tiled<<<dim3(1024 / 64, 8192 / 64), 256, 0, stream>>>(
      attn_o, W_out, outp, 8192, 1024, 512, b_out, x, nullptr);
}

// Round 2
// 336.669 us; speedup vs baseline: 7.8508x; 7.8508x over previous
//
#include <hip/hip_runtime.h>
#include <math.h>

typedef __bf16 bf16;
typedef __attribute__((ext_vector_type(8))) __bf16 bf16x8;
typedef __attribute__((ext_vector_type(4))) float f32x4;

#define MFMA16(a, b, c) __builtin_amdgcn_mfma_f32_16x16x32_bf16(a, b, c, 0, 0, 0)

// ---------------- fp32 -> bf16 convert (vectorized)
__global__ __launch_bounds__(256) void conv_bf16_kernel(const float* __restrict__ in,
                                                        bf16* __restrict__ out) {
  int idx = blockIdx.x * 256 + threadIdx.x;
  const float4 a = ((const float4*)in)[idx * 2];
  const float4 b = ((const float4*)in)[idx * 2 + 1];
  bf16x8 o = {(bf16)a.x, (bf16)a.y, (bf16)a.z, (bf16)a.w,
              (bf16)b.x, (bf16)b.y, (bf16)b.z, (bf16)b.w};
  *(bf16x8*)(out + (size_t)idx * 8) = o;
}

// ---------------- W[K][N] fp32 -> WT[N][K] bf16
__global__ __launch_bounds__(256) void transpose_to_bf16(const float* __restrict__ W,
                                                         bf16* __restrict__ WT,
                                                         int K, int N) {
  __shared__ float tile[32][33];
  const int n0 = blockIdx.x * 32, k0 = blockIdx.y * 32;
  const int tx = threadIdx.x & 31, ty = threadIdx.x >> 5;
#pragma unroll
  for (int i = 0; i < 4; ++i)
    tile[ty + 8 * i][tx] = W[(size_t)(k0 + ty + 8 * i) * N + n0 + tx];
  __syncthreads();
#pragma unroll
  for (int i = 0; i < 4; ++i)
    WT[(size_t)(n0 + ty + 8 * i) * K + k0 + tx] = (bf16)tile[tx][ty + 8 * i];
}

// ---------------- v part of qkv -> vT[b*512 + c][n]  (c = h*64+d)
__global__ __launch_bounds__(256) void vtrans_kernel(const bf16* __restrict__ qkv,
                                                     bf16* __restrict__ vT) {
  __shared__ bf16 tile[32][34];
  const int b = blockIdx.z;
  const int n0 = blockIdx.x * 32, c0 = blockIdx.y * 32;
  const int tx = threadIdx.x & 31, ty = threadIdx.x >> 5;
#pragma unroll
  for (int i = 0; i < 4; ++i)
    tile[ty + 8 * i][tx] = qkv[(size_t)(b * 1024 + n0 + ty + 8 * i) * 2560 + 2048 + c0 + tx];
  __syncthreads();
#pragma unroll
  for (int i = 0; i < 4; ++i)
    vT[(size_t)(b * 512 + c0 + ty + 8 * i) * 1024 + n0 + tx] = tile[tx][ty + 8 * i];
}

// ---------------- pe_proj: pe(1024x32) @ W_pos[1024:1056,:] -> (1024,1024) fp32
__global__ __launch_bounds__(256) void pe_proj_kernel(const float* __restrict__ pe,
                                                      const float* __restrict__ W_pos,
                                                      float* __restrict__ out) {
  int idx = blockIdx.x * 256 + threadIdx.x;
  int n = idx >> 10, c = idx & 1023;
  float s = 0.f;
#pragma unroll
  for (int e = 0; e < 32; ++e)
    s += pe[n * 32 + e] * W_pos[(size_t)(1024 + e) * 1024 + c];
  out[idx] = s;
}

// ---------------- bf16 MFMA GEMM: C[M,N] = A[M,K] @ BT[N,K]^T (+bias +add_full +add_mod)
// 128x128 tile, BK=64, 256 threads = 4 waves (2x2), each wave 64x64 (4x4 16x16 frags)
template <int OUT_BF16>
__global__ __launch_bounds__(256) void gemm_bf16(
    const bf16* __restrict__ A, const bf16* __restrict__ BT, void* __restrict__ Cout,
    int M, int N, int K,
    const float* __restrict__ bias, const float* __restrict__ add_full,
    const float* __restrict__ add_mod) {
  __shared__ __align__(16) bf16 As[128 * 64];
  __shared__ __align__(16) bf16 Bs[128 * 64];
  const int tid = threadIdx.x;
  const int wave = tid >> 6, lane = tid & 63;
  const int wr = wave >> 1, wc = wave & 1;
  const int lr = lane & 15, lg = lane >> 4;
  const int row0 = blockIdx.y * 128, col0 = blockIdx.x * 128;
  f32x4 acc[4][4] = {};
  const int srow = tid >> 1, shalf = (tid & 1) * 32;
  const size_t a_base = (size_t)(row0 + srow) * K + shalf;
  const size_t b_base = (size_t)(col0 + srow) * K + shalf;
  const int wbyte0 = srow * 128;
  const int wswz = (srow & 7) << 4;

  for (int kt = 0; kt < K; kt += 64) {
#pragma unroll
    for (int i = 0; i < 4; ++i) {
      bf16x8 va = *(const bf16x8*)(A + a_base + kt + 8 * i);
      bf16x8 vb = *(const bf16x8*)(BT + b_base + kt + 8 * i);
      int byte = wbyte0 + (((shalf + 8 * i) * 2) ^ wswz);
      *(bf16x8*)((char*)As + byte) = va;
      *(bf16x8*)((char*)Bs + byte) = vb;
    }
    __syncthreads();
#pragma unroll
    for (int kc = 0; kc < 2; ++kc) {
      bf16x8 af[4], bfr[4];
#pragma unroll
      for (int mt = 0; mt < 4; ++mt) {
        int r = wr * 64 + mt * 16 + lr;
        int byte = r * 128 + (((kc * 32 + lg * 8) * 2) ^ ((r & 7) << 4));
        af[mt] = *(const bf16x8*)((const char*)As + byte);
      }
#pragma unroll
      for (int nt = 0; nt < 4; ++nt) {
        int c = wc * 64 + nt * 16 + lr;
        int byte = c * 128 + (((kc * 32 + lg * 8) * 2) ^ ((c & 7) << 4));
        bfr[nt] = *(const bf16x8*)((const char*)Bs + byte);
      }
#pragma unroll
      for (int mt = 0; mt < 4; ++mt)
#pragma unroll
        for (int nt = 0; nt < 4; ++nt)
          acc[mt][nt] = MFMA16(af[mt], bfr[nt], acc[mt][nt]);
    }
    __syncthreads();
  }
#pragma unroll
  for (int mt = 0; mt < 4; ++mt) {
#pragma unroll
    for (int v = 0; v < 4; ++v) {
      int r = row0 + wr * 64 + mt * 16 + lg * 4 + v;
#pragma unroll
      for (int nt = 0; nt < 4; ++nt) {
        int c = col0 + wc * 64 + nt * 16 + lr;
        float val = acc[mt][nt][v];
        if (bias) val += bias[c];
        if (add_full) val += add_full[(size_t)r * N + c];
        if (add_mod) val += add_mod[(size_t)(r & 1023) * N + c];
        if (OUT_BF16)
          ((bf16*)Cout)[(size_t)r * N + c] = (bf16)val;
        else
          ((float*)Cout)[(size_t)r * N + c] = val;
      }
    }
  }
}

// ---------------- FeatureNorm over sequence dim; h fp32 in, hn bf16 out
__global__ __launch_bounds__(512) void featnorm_kernel(const float* __restrict__ h,
                                                       bf16* __restrict__ hn,
                                                       const float* __restrict__ gamma,
                                                       const float* __restrict__ beta) {
  const int b = blockIdx.x >> 4;
  const int d0 = (blockIdx.x & 15) << 6;
  const int tid = threadIdx.x;
  const int c = tid & 63, g = tid >> 6;
  const size_t base = (size_t)b * (1024 * 1024) + d0 + c;
  float s = 0.f, s2 = 0.f;
  for (int n = g * 128; n < g * 128 + 128; ++n) {
    float v = h[base + (size_t)n * 1024];
    s += v; s2 += v * v;
  }
  __shared__ float rs[8][64], rs2[8][64];
  rs[g][c] = s; rs2[g][c] = s2;
  __syncthreads();
  __shared__ float smean[64], srstd[64];
  if (tid < 64) {
    float S = 0.f, S2 = 0.f;
#pragma unroll
    for (int q = 0; q < 8; ++q) { S += rs[q][tid]; S2 += rs2[q][tid]; }
    float mean = S * (1.f / 1024.f);
    float var = S2 * (1.f / 1024.f) - mean * mean;
    smean[tid] = mean;
    srstd[tid] = rsqrtf(var + 1e-5f);
  }
  __syncthreads();
  const float mean = smean[c], rstd = srstd[c];
  const float gm = gamma[d0 + c], bt = beta[d0 + c];
  for (int n = g * 128; n < g * 128 + 128; ++n) {
    size_t idx = base + (size_t)n * 1024;
    hn[idx] = (bf16)(gm * (h[idx] - mean) * rstd + bt);
  }
}

// ---------------- squared norms of q,k rows (from the bf16 values attention consumes)
__global__ __launch_bounds__(128) void sqsk_kernel(const bf16* __restrict__ qkv,
                                                   float* __restrict__ sqb,
                                                   float* __restrict__ skb) {
  const int bid = blockIdx.x;  // (b*8+h)*1024 + n
  const int n = bid & 1023, bh = bid >> 10;
  const int b = bh >> 3, hh = bh & 7;
  const int tid = threadIdx.x;
  const int grp = tid >> 6, lane = tid & 63;
  size_t basep = (size_t)(b * 1024 + n) * 2560 + (grp ? 1024 : 0) + hh * 128;
  float v0 = (float)qkv[basep + lane], v1 = (float)qkv[basep + 64 + lane];
  float s = v0 * v0 + v1 * v1;
#pragma unroll
  for (int off = 32; off; off >>= 1) s += __shfl_down(s, off);
  if (lane == 0) { if (grp) skb[bid] = s; else sqb[bid] = s; }
}

// ---------------- MFMA distance attention. grid = B*H*(N/64) = 1024, 256 thr = 4 waves
__global__ __launch_bounds__(256) void attn_mfma(const bf16* __restrict__ qkv,
                                                 const bf16* __restrict__ vT,
                                                 const float* __restrict__ sqb,
                                                 const float* __restrict__ skb,
                                                 const float* __restrict__ scale_ptr,
                                                 bf16* __restrict__ attn_o) {
  const int blk = blockIdx.x;  // (b*8+h)*16 + it
  const int it = blk & 15, bh = blk >> 4;
  const int b = bh >> 3, h = bh & 7;
  const int i0 = it * 64;
  const int tid = threadIdx.x, wave = tid >> 6, lane = tid & 63;
  const int lr = lane & 15, lg = lane >> 4;
  const float sc = scale_ptr[0];
  const float invs2 = 1.f / (sc * sc);

  __shared__ __align__(16) bf16 Ks[64 * 128];
  __shared__ __align__(16) bf16 Vs[64 * 64];   // [d][j] swizzled
  __shared__ __align__(16) bf16 Ps[4][16 * 64];
  __shared__ float sqs[64], sks[64];

  bf16x8 qf[4];
  {
    const bf16* qrow = qkv + (size_t)(b * 1024 + i0 + wave * 16 + lr) * 2560 + h * 128;
#pragma unroll
    for (int kc = 0; kc < 4; ++kc) qf[kc] = *(const bf16x8*)(qrow + kc * 32 + lg * 8);
  }
  if (tid < 64) sqs[tid] = sqb[bh * 1024 + i0 + tid];

  float m[4], lsum[4];
  f32x4 o[4] = {};
#pragma unroll
  for (int v = 0; v < 4; ++v) { m[v] = -1e30f; lsum[v] = 0.f; }

  for (int jt = 0; jt < 16; ++jt) {
    __syncthreads();
    {  // stage K tile (64 x 128), row-swizzled
      int j = tid >> 2, q = tid & 3;
      const bf16* krow = qkv + (size_t)(b * 1024 + jt * 64 + j) * 2560 + 1024 + h * 128 + q * 32;
      int swz = (j & 7) << 4;
#pragma unroll
      for (int i = 0; i < 4; ++i) {
        bf16x8 kv = *(const bf16x8*)(krow + i * 8);
        int byte = j * 256 + (((q * 32 + i * 8) * 2) ^ swz);
        *(bf16x8*)((char*)Ks + byte) = kv;
      }
    }
    {  // stage V tile as [d][j], row-swizzled, from pre-transposed vT
      int d = tid >> 2, j0 = (tid & 3) * 16;
      const bf16* vrow = vT + (size_t)(b * 512 + h * 64 + d) * 1024 + jt * 64 + j0;
      int swz = (d & 7) << 4;
#pragma unroll
      for (int i = 0; i < 2; ++i) {
        bf16x8 vv = *(const bf16x8*)(vrow + i * 8);
        int byte = d * 128 + (((j0 + i * 8) * 2) ^ swz);
        *(bf16x8*)((char*)Vs + byte) = vv;
      }
    }
    if (tid < 64) sks[tid] = skb[bh * 1024 + jt * 64 + tid];
    __syncthreads();

    // QK^T: S strip 16x64 per wave
    f32x4 sacc[4] = {};
#pragma unroll
    for (int kc = 0; kc < 4; ++kc) {
#pragma unroll
      for (int nt = 0; nt < 4; ++nt) {
        int j = nt * 16 + lr;
        int byte = j * 256 + (((kc * 32 + lg * 8) * 2) ^ ((j & 7) << 4));
        bf16x8 kf = *(const bf16x8*)((const char*)Ks + byte);
        sacc[nt] = MFMA16(qf[kc], kf, sacc[nt]);
      }
    }

    // d2 -> logits, online softmax (rows owned by (lg, v), reduce over 16 lr lanes)
    float p[4][4], tm[4];
#pragma unroll
    for (int v = 0; v < 4; ++v) tm[v] = -1e30f;
#pragma unroll
    for (int nt = 0; nt < 4; ++nt) {
      float sk_j = sks[nt * 16 + lr];
#pragma unroll
      for (int v = 0; v < 4; ++v) {
        float d2 = sqs[wave * 16 + lg * 4 + v] + sk_j - 2.f * sacc[nt][v];
        d2 = fmaxf(d2, 0.f);
        float sv = -d2 * invs2;
        p[nt][v] = sv;
        tm[v] = fmaxf(tm[v], sv);
      }
    }
#pragma unroll
    for (int off = 1; off < 16; off <<= 1)
#pragma unroll
      for (int v = 0; v < 4; ++v) tm[v] = fmaxf(tm[v], __shfl_xor(tm[v], off));
    float ps[4];
#pragma unroll
    for (int v = 0; v < 4; ++v) {
      float mn = fmaxf(m[v], tm[v]);
      float corr = __expf(m[v] - mn);
      m[v] = mn;
      lsum[v] *= corr;
#pragma unroll
      for (int nt = 0; nt < 4; ++nt) o[nt][v] *= corr;
      ps[v] = 0.f;
#pragma unroll
      for (int nt = 0; nt < 4; ++nt) {
        float pv = __expf(p[nt][v] - mn);
        p[nt][v] = pv;
        ps[v] += pv;
      }
    }
#pragma unroll
    for (int off = 1; off < 16; off <<= 1)
#pragma unroll
      for (int v = 0; v < 4; ++v) ps[v] += __shfl_xor(ps[v], off);
#pragma unroll
    for (int v = 0; v < 4; ++v) lsum[v] += ps[v];

    // P -> wave-private LDS (swizzled), then PV MFMA
#pragma unroll
    for (int nt = 0; nt < 4; ++nt)
#pragma unroll
      for (int v = 0; v < 4; ++v) {
        int r = lg * 4 + v, c = nt * 16 + lr;
        int byte = r * 128 + ((c * 2) ^ ((r & 7) << 4));
        *(bf16*)((char*)&Ps[wave][0] + byte) = (bf16)p[nt][v];
      }
    bf16x8 pf[2];
#pragma unroll
    for (int kc = 0; kc < 2; ++kc) {
      int byte = lr * 128 + (((kc * 32 + lg * 8) * 2) ^ ((lr & 7) << 4));
      pf[kc] = *(const bf16x8*)((const char*)&Ps[wave][0] + byte);
    }
#pragma unroll
    for (int kc = 0; kc < 2; ++kc)
#pragma unroll
      for (int nt = 0; nt < 4; ++nt) {
        int d = nt * 16 + lr;
        int byte = d * 128 + (((kc * 32 + lg * 8) * 2) ^ ((d & 7) << 4));
        bf16x8 vf = *(const bf16x8*)((const char*)Vs + byte);
        o[nt] = MFMA16(pf[kc], vf, o[nt]);
      }
  }

#pragma unroll
  for (int nt = 0; nt < 4; ++nt)
#pragma unroll
    for (int v = 0; v < 4; ++v) {
      int r = i0 + wave * 16 + lg * 4 + v;
      int c = h * 64 + nt * 16 + lr;
      attn_o[(size_t)(b * 1024 + r) * 512 + c] = (bf16)(o[nt][v] / lsum[v]);
    }
}

extern "C" void kernel_launch(void* const* d_in, const int* in_sizes, int n_in,
                              void* d_out, int out_size, void* d_ws, size_t ws_size,
                              hipStream_t stream) {
  const float* x     = (const float*)d_in[0];
  const float* gamma = (const float*)d_in[1];
  const float* beta  = (const float*)d_in[2];
  const float* pe    = (const float*)d_in[3];
  const float* W_pos = (const float*)d_in[4];
  const float* b_pos = (const float*)d_in[5];
  const float* W_qkv = (const float*)d_in[6];
  const float* b_qkv = (const float*)d_in[7];
  const float* W_out = (const float*)d_in[8];
  const float* b_out = (const float*)d_in[9];
  const float* scale = (const float*)d_in[10];
  float* outp = (float*)d_out;

  char* ws = (char*)d_ws;
  const size_t MB = 1 << 20;
  bf16* x_bf    = (bf16*)(ws);              // 16MB, reused as hn_bf after GEMM1
  bf16* wpos_t  = (bf16*)(ws + 16 * MB);    // 2MB
  bf16* wqkv_t  = (bf16*)(ws + 18 * MB);    // 5MB
  bf16* wout_t  = (bf16*)(ws + 23 * MB);    // 1MB
  float* pe_pj  = (float*)(ws + 24 * MB);   // 4MB
  float* h      = (float*)(ws + 28 * MB);   // 32MB, dead after featnorm
  bf16* vT      = (bf16*)(ws + 28 * MB);    // 8MB (aliases h, used after)
  bf16* attn_o  = (bf16*)(ws + 36 * MB);    // 8MB (aliases h)
  bf16* qkv     = (bf16*)(ws + 60 * MB);    // 40MB
  float* sqb    = (float*)(ws + 100 * MB);  // 256KB
  float* skb    = (float*)(ws + 100 * MB + 262144);
  bf16* hn_bf   = x_bf;

  // pre-passes
  conv_bf16_kernel<<<4096, 256, 0, stream>>>(x, x_bf);
  transpose_to_bf16<<<dim3(32, 32), 256, 0, stream>>>(W_pos, wpos_t, 1024, 1024);
  transpose_to_bf16<<<dim3(80, 32), 256, 0, stream>>>(W_qkv, wqkv_t, 1024, 2560);
  transpose_to_bf16<<<dim3(32, 16), 256, 0, stream>>>(W_out, wout_t, 512, 1024);
  pe_proj_kernel<<<4096, 256, 0, stream>>>(pe, W_pos, pe_pj);
  // h = x + x@W_pos + pe + b_pos   (fp32 out)
  gemm_bf16<0><<<dim3(8, 64), 256, 0, stream>>>(x_bf, wpos_t, h, 8192, 1024, 1024,
                                                b_pos, x, pe_pj);
  // featurenorm over sequence -> hn bf16
  featnorm_kernel<<<128, 512, 0, stream>>>(h, hn_bf, gamma, beta);
  // qkv = hn @ W_qkv + b_qkv  (bf16 out)
  gemm_bf16<1><<<dim3(20, 64), 256, 0, stream>>>(hn_bf, wqkv_t, qkv, 8192, 2560, 1024,
                                                 b_qkv, nullptr, nullptr);
  sqsk_kernel<<<65536, 128, 0, stream>>>(qkv, sqb, skb);
  vtrans_kernel<<<dim3(32, 16, 8), 256, 0, stream>>>(qkv, vT);
  attn_mfma<<<1024, 256, 0, stream>>>(qkv, vT, sqb, skb, scale, attn_o);
  // out = x + attn_o @ W_out + b_out  (fp32 out)
  gemm_bf16<0><<<dim3(8, 64), 256, 0, stream>>>(attn_o, wout_t, outp, 8192, 1024, 512,
                                                b_out, x, nullptr);
}

// Round 3
// 330.535 us; speedup vs baseline: 7.9965x; 1.0186x over previous
//
#include <hip/hip_runtime.h>
#include <math.h>

typedef __bf16 bf16;
typedef __attribute__((ext_vector_type(8))) __bf16 bf16x8;
typedef __attribute__((ext_vector_type(4))) float f32x4;

#define MFMA16(a, b, c) __builtin_amdgcn_mfma_f32_16x16x32_bf16(a, b, c, 0, 0, 0)

__device__ __forceinline__ void gld_lds16(const void* g, void* l) {
  __builtin_amdgcn_global_load_lds(
      (const __attribute__((address_space(1))) unsigned int*)g,
      (__attribute__((address_space(3))) unsigned int*)l, 16, 0, 0);
}

// ---------------- fp32 -> bf16 convert (vectorized)
__global__ __launch_bounds__(256) void conv_bf16_kernel(const float* __restrict__ in,
                                                        bf16* __restrict__ out) {
  int idx = blockIdx.x * 256 + threadIdx.x;
  const float4 a = ((const float4*)in)[idx * 2];
  const float4 b = ((const float4*)in)[idx * 2 + 1];
  bf16x8 o = {(bf16)a.x, (bf16)a.y, (bf16)a.z, (bf16)a.w,
              (bf16)b.x, (bf16)b.y, (bf16)b.z, (bf16)b.w};
  *(bf16x8*)(out + (size_t)idx * 8) = o;
}

// ---------------- W[K][N] fp32 -> WT[N][K] bf16
__global__ __launch_bounds__(256) void transpose_to_bf16(const float* __restrict__ W,
                                                         bf16* __restrict__ WT,
                                                         int K, int N) {
  __shared__ float tile[32][33];
  const int n0 = blockIdx.x * 32, k0 = blockIdx.y * 32;
  const int tx = threadIdx.x & 31, ty = threadIdx.x >> 5;
#pragma unroll
  for (int i = 0; i < 4; ++i)
    tile[ty + 8 * i][tx] = W[(size_t)(k0 + ty + 8 * i) * N + n0 + tx];
  __syncthreads();
#pragma unroll
  for (int i = 0; i < 4; ++i)
    WT[(size_t)(n0 + ty + 8 * i) * K + k0 + tx] = (bf16)tile[tx][ty + 8 * i];
}

// ---------------- v part of qkv -> vT[b*512 + c][n]  (c = h*64+d)
__global__ __launch_bounds__(256) void vtrans_kernel(const bf16* __restrict__ qkv,
                                                     bf16* __restrict__ vT) {
  __shared__ bf16 tile[32][34];
  const int b = blockIdx.z;
  const int n0 = blockIdx.x * 32, c0 = blockIdx.y * 32;
  const int tx = threadIdx.x & 31, ty = threadIdx.x >> 5;
#pragma unroll
  for (int i = 0; i < 4; ++i)
    tile[ty + 8 * i][tx] = qkv[(size_t)(b * 1024 + n0 + ty + 8 * i) * 2560 + 2048 + c0 + tx];
  __syncthreads();
#pragma unroll
  for (int i = 0; i < 4; ++i)
    vT[(size_t)(b * 512 + c0 + ty + 8 * i) * 1024 + n0 + tx] = tile[tx][ty + 8 * i];
}

// ---------------- pe_proj: pe(1024x32) @ W_pos[1024:1056,:] -> (1024,1024) bf16
__global__ __launch_bounds__(256) void pe_proj_kernel(const float* __restrict__ pe,
                                                      const float* __restrict__ W_pos,
                                                      bf16* __restrict__ out) {
  int idx = blockIdx.x * 256 + threadIdx.x;
  int n = idx >> 10, c = idx & 1023;
  float s = 0.f;
#pragma unroll
  for (int e = 0; e < 32; ++e)
    s += pe[n * 32 + e] * W_pos[(size_t)(1024 + e) * 1024 + c];
  out[idx] = (bf16)s;
}

// ---------------- bf16 MFMA GEMM (m97 structure): C[M,N] = A[M,K] @ BT[N,K]^T
// 128x128 tile, BK=64, 256 threads = 4 waves (2x2), global_load_lds staging with
// pre-swizzled source (rule 21: linear dest + inverse-swizzled source + swizzled read).
template <int OUT_BF16>
__global__ __launch_bounds__(256) void gemm_bf16(
    const bf16* __restrict__ A, const bf16* __restrict__ BT, void* __restrict__ Cout,
    int M, int N, int K,
    const float* __restrict__ bias, const float* __restrict__ add_full,
    const bf16* __restrict__ add_mod) {
  __shared__ __align__(16) bf16 As[128 * 64];
  __shared__ __align__(16) bf16 Bs[128 * 64];
  const int tid = threadIdx.x;
  const int wave = tid >> 6, lane = tid & 63;
  const int wr = wave >> 1, wc = wave & 1;
  const int lr = lane & 15, lg = lane >> 4;
  const int row0 = blockIdx.y * 128, col0 = blockIdx.x * 128;
  // staging: LDS linear byte o = c*4096 + tid*16 -> row = c*32 + (tid>>3), colbyte = (tid&7)*16
  const int trow = tid >> 3;
  const int cb = (tid & 7) * 16;
  const int cbd = cb ^ ((trow & 7) << 4);  // inverse-swizzled source column (bytes)
  const bf16* asrc = A + (size_t)(row0 + trow) * K + (cbd >> 1);
  const bf16* bsrc = BT + (size_t)(col0 + trow) * K + (cbd >> 1);
  char* al = (char*)As + tid * 16;
  char* bl = (char*)Bs + tid * 16;
  f32x4 acc[4][4] = {};

  for (int kt = 0; kt < K; kt += 64) {
#pragma unroll
    for (int c = 0; c < 4; ++c) {
      gld_lds16(asrc + (size_t)c * 32 * K + kt, al + c * 4096);
      gld_lds16(bsrc + (size_t)c * 32 * K + kt, bl + c * 4096);
    }
    __syncthreads();
#pragma unroll
    for (int kc = 0; kc < 2; ++kc) {
      bf16x8 af[4], bfr[4];
#pragma unroll
      for (int mt = 0; mt < 4; ++mt) {
        int r = wr * 64 + mt * 16 + lr;
        int byte = r * 128 + (((kc * 32 + lg * 8) * 2) ^ ((r & 7) << 4));
        af[mt] = *(const bf16x8*)((const char*)As + byte);
      }
#pragma unroll
      for (int nt = 0; nt < 4; ++nt) {
        int c = wc * 64 + nt * 16 + lr;
        int byte = c * 128 + (((kc * 32 + lg * 8) * 2) ^ ((c & 7) << 4));
        bfr[nt] = *(const bf16x8*)((const char*)Bs + byte);
      }
#pragma unroll
      for (int mt = 0; mt < 4; ++mt)
#pragma unroll
        for (int nt = 0; nt < 4; ++nt)
          acc[mt][nt] = MFMA16(af[mt], bfr[nt], acc[mt][nt]);
    }
    __syncthreads();
  }
#pragma unroll
  for (int mt = 0; mt < 4; ++mt) {
#pragma unroll
    for (int v = 0; v < 4; ++v) {
      int r = row0 + wr * 64 + mt * 16 + lg * 4 + v;
#pragma unroll
      for (int nt = 0; nt < 4; ++nt) {
        int c = col0 + wc * 64 + nt * 16 + lr;
        float val = acc[mt][nt][v];
        if (bias) val += bias[c];
        if (add_full) val += add_full[(size_t)r * N + c];
        if (add_mod) val += (float)add_mod[(size_t)(r & 1023) * N + c];
        if (OUT_BF16)
          ((bf16*)Cout)[(size_t)r * N + c] = (bf16)val;
        else
          ((float*)Cout)[(size_t)r * N + c] = val;
      }
    }
  }
}

// ---------------- FeatureNorm over sequence dim; h bf16 in, hn bf16 out
__global__ __launch_bounds__(512) void featnorm_kernel(const bf16* __restrict__ h,
                                                       bf16* __restrict__ hn,
                                                       const float* __restrict__ gamma,
                                                       const float* __restrict__ beta) {
  const int b = blockIdx.x >> 4;
  const int d0 = (blockIdx.x & 15) << 6;
  const int tid = threadIdx.x;
  const int c = tid & 63, g = tid >> 6;
  const size_t base = (size_t)b * (1024 * 1024) + d0 + c;
  float s = 0.f, s2 = 0.f;
  for (int n = g * 128; n < g * 128 + 128; ++n) {
    float v = (float)h[base + (size_t)n * 1024];
    s += v; s2 += v * v;
  }
  __shared__ float rs[8][64], rs2[8][64];
  rs[g][c] = s; rs2[g][c] = s2;
  __syncthreads();
  __shared__ float smean[64], srstd[64];
  if (tid < 64) {
    float S = 0.f, S2 = 0.f;
#pragma unroll
    for (int q = 0; q < 8; ++q) { S += rs[q][tid]; S2 += rs2[q][tid]; }
    float mean = S * (1.f / 1024.f);
    float var = S2 * (1.f / 1024.f) - mean * mean;
    smean[tid] = mean;
    srstd[tid] = rsqrtf(var + 1e-5f);
  }
  __syncthreads();
  const float mean = smean[c], rstd = srstd[c];
  const float gm = gamma[d0 + c], bt = beta[d0 + c];
  for (int n = g * 128; n < g * 128 + 128; ++n) {
    size_t idx = base + (size_t)n * 1024;
    hn[idx] = (bf16)(gm * ((float)h[idx] - mean) * rstd + bt);
  }
}

// ---------------- squared norms of q,k rows: 16 lanes/row, bf16x8 loads
__global__ __launch_bounds__(256) void sqsk_kernel(const bf16* __restrict__ qkv,
                                                   float* __restrict__ sqb,
                                                   float* __restrict__ skb) {
  const int tid = threadIdx.x;
  const int lr = tid & 15;
  const int task = blockIdx.x * 16 + (tid >> 4);  // [0, 131072)
  const int qk = task >> 16;
  const int bhn = task & 65535;
  const int bh = bhn >> 10, n = bhn & 1023;
  const int b = bh >> 3, h = bh & 7;
  const bf16x8 v = *(const bf16x8*)(qkv + (size_t)(b * 1024 + n) * 2560 +
                                    qk * 1024 + h * 128 + lr * 8);
  float s = 0.f;
#pragma unroll
  for (int i = 0; i < 8; ++i) { float f = (float)v[i]; s += f * f; }
#pragma unroll
  for (int off = 1; off < 16; off <<= 1) s += __shfl_xor(s, off);
  if (lr == 0) (qk ? skb : sqb)[bhn] = s;
}

// ---------------- MFMA distance attention, double-buffered async staging.
// grid = B*H*(N/64) = 1024, 256 thr = 4 waves (16 Q-rows each)
__global__ __launch_bounds__(256) void attn_mfma(const bf16* __restrict__ qkv,
                                                 const bf16* __restrict__ vT,
                                                 const float* __restrict__ sqb,
                                                 const float* __restrict__ skb,
                                                 const float* __restrict__ scale_ptr,
                                                 bf16* __restrict__ attn_o) {
  const int blk = blockIdx.x;  // (b*8+h)*16 + it
  const int it = blk & 15, bh = blk >> 4;
  const int b = bh >> 3, h = bh & 7;
  const int i0 = it * 64;
  const int tid = threadIdx.x, wave = tid >> 6, lane = tid & 63;
  const int lr = lane & 15, lg = lane >> 4;
  const float sc = scale_ptr[0];
  const float invs2 = 1.f / (sc * sc);

  __shared__ __align__(16) bf16 Ks[2][64 * 128];  // [j][d], swizzled content
  __shared__ __align__(16) bf16 Vs[2][64 * 64];   // [d][j], swizzled content
  __shared__ __align__(16) bf16 Ps[4][16 * 64];

  // staging addressing (rule 21: linear LDS dest, inverse-swizzled global source)
  const int trowK = tid >> 4;                 // K row = 256B -> 16 thr/row
  const int cbKd = ((tid & 15) * 16) ^ ((trowK & 7) << 4);
  const bf16* ksrc = qkv + (size_t)(b * 1024 + trowK) * 2560 + 1024 + h * 128 + (cbKd >> 1);
  const int trowV = tid >> 3;                 // V row = 128B -> 8 thr/row
  const int cbVd = ((tid & 7) * 16) ^ ((trowV & 7) << 4);
  const bf16* vsrc = vT + (size_t)(b * 512 + h * 64 + trowV) * 1024 + (cbVd >> 1);

  auto STAGE = [&](int sel, int jt) {
    const bf16* kp = ksrc + (size_t)jt * 64 * 2560;
    char* kl = (char*)&Ks[sel][0] + tid * 16;
#pragma unroll
    for (int c = 0; c < 4; ++c)
      gld_lds16(kp + (size_t)c * 16 * 2560, kl + c * 4096);
    const bf16* vp = vsrc + jt * 64;
    char* vl = (char*)&Vs[sel][0] + tid * 16;
#pragma unroll
    for (int c = 0; c < 2; ++c)
      gld_lds16(vp + c * 32 * 1024, vl + c * 4096);
  };

  // Q fragments in registers
  bf16x8 qf[4];
  {
    const bf16* qrow = qkv + (size_t)(b * 1024 + i0 + wave * 16 + lr) * 2560 + h * 128;
#pragma unroll
    for (int kc = 0; kc < 4; ++kc) qf[kc] = *(const bf16x8*)(qrow + kc * 32 + lg * 8);
  }
  float sqv[4];
#pragma unroll
  for (int v = 0; v < 4; ++v) sqv[v] = sqb[bh * 1024 + i0 + wave * 16 + lg * 4 + v];

  float m[4], lsum[4];
  f32x4 o[4] = {};
#pragma unroll
  for (int v = 0; v < 4; ++v) { m[v] = -1e30f; lsum[v] = 0.f; }

  STAGE(0, 0);
  __syncthreads();
  int cur = 0;

  for (int jt = 0; jt < 16; ++jt) {
    if (jt < 15) STAGE(cur ^ 1, jt + 1);  // async prefetch next tile

    float sk_j[4];
#pragma unroll
    for (int nt = 0; nt < 4; ++nt) sk_j[nt] = skb[bh * 1024 + jt * 64 + nt * 16 + lr];

    // QK^T: S strip 16x64 per wave
    f32x4 sacc[4] = {};
    __builtin_amdgcn_s_setprio(1);
#pragma unroll
    for (int kc = 0; kc < 4; ++kc) {
#pragma unroll
      for (int nt = 0; nt < 4; ++nt) {
        int j = nt * 16 + lr;
        int byte = j * 256 + (((kc * 32 + lg * 8) * 2) ^ ((j & 7) << 4));
        bf16x8 kf = *(const bf16x8*)((const char*)&Ks[cur][0] + byte);
        sacc[nt] = MFMA16(qf[kc], kf, sacc[nt]);
      }
    }
    __builtin_amdgcn_s_setprio(0);

    // d2 -> logits, online softmax (rows owned by (lg, v), reduce over 16 lr lanes)
    float p[4][4], tm[4];
#pragma unroll
    for (int v = 0; v < 4; ++v) tm[v] = -1e30f;
#pragma unroll
    for (int nt = 0; nt < 4; ++nt) {
#pragma unroll
      for (int v = 0; v < 4; ++v) {
        float d2 = sqv[v] + sk_j[nt] - 2.f * sacc[nt][v];
        d2 = fmaxf(d2, 0.f);
        float sv = -d2 * invs2;
        p[nt][v] = sv;
        tm[v] = fmaxf(tm[v], sv);
      }
    }
#pragma unroll
    for (int off = 1; off < 16; off <<= 1)
#pragma unroll
      for (int v = 0; v < 4; ++v) tm[v] = fmaxf(tm[v], __shfl_xor(tm[v], off));
    float ps[4];
#pragma unroll
    for (int v = 0; v < 4; ++v) {
      float mn = fmaxf(m[v], tm[v]);
      float corr = __expf(m[v] - mn);
      m[v] = mn;
      lsum[v] *= corr;
#pragma unroll
      for (int nt = 0; nt < 4; ++nt) o[nt][v] *= corr;
      ps[v] = 0.f;
#pragma unroll
      for (int nt = 0; nt < 4; ++nt) {
        float pv = __expf(p[nt][v] - mn);
        p[nt][v] = pv;
        ps[v] += pv;
      }
    }
#pragma unroll
    for (int off = 1; off < 16; off <<= 1)
#pragma unroll
      for (int v = 0; v < 4; ++v) ps[v] += __shfl_xor(ps[v], off);
#pragma unroll
    for (int v = 0; v < 4; ++v) lsum[v] += ps[v];

    // P -> wave-private LDS (swizzled), then PV MFMA
#pragma unroll
    for (int nt = 0; nt < 4; ++nt)
#pragma unroll
      for (int v = 0; v < 4; ++v) {
        int r = lg * 4 + v, c = nt * 16 + lr;
        int byte = r * 128 + ((c * 2) ^ ((r & 7) << 4));
        *(bf16*)((char*)&Ps[wave][0] + byte) = (bf16)p[nt][v];
      }
    bf16x8 pf[2];
#pragma unroll
    for (int kc = 0; kc < 2; ++kc) {
      int byte = lr * 128 + (((kc * 32 + lg * 8) * 2) ^ ((lr & 7) << 4));
      pf[kc] = *(const bf16x8*)((const char*)&Ps[wave][0] + byte);
    }
    __builtin_amdgcn_s_setprio(1);
#pragma unroll
    for (int kc = 0; kc < 2; ++kc)
#pragma unroll
      for (int nt = 0; nt < 4; ++nt) {
        int d = nt * 16 + lr;
        int byte = d * 128 + (((kc * 32 + lg * 8) * 2) ^ ((d & 7) << 4));
        bf16x8 vf = *(const bf16x8*)((const char*)&Vs[cur][0] + byte);
        o[nt] = MFMA16(pf[kc], vf, o[nt]);
      }
    __builtin_amdgcn_s_setprio(0);

    __syncthreads();  // vmcnt(0) drain of prefetch + buffer handoff
    cur ^= 1;
  }

#pragma unroll
  for (int nt = 0; nt < 4; ++nt)
#pragma unroll
    for (int v = 0; v < 4; ++v) {
      int r = i0 + wave * 16 + lg * 4 + v;
      int c = h * 64 + nt * 16 + lr;
      attn_o[(size_t)(b * 1024 + r) * 512 + c] = (bf16)(o[nt][v] / lsum[v]);
    }
}

extern "C" void kernel_launch(void* const* d_in, const int* in_sizes, int n_in,
                              void* d_out, int out_size, void* d_ws, size_t ws_size,
                              hipStream_t stream) {
  const float* x     = (const float*)d_in[0];
  const float* gamma = (const float*)d_in[1];
  const float* beta  = (const float*)d_in[2];
  const float* pe    = (const float*)d_in[3];
  const float* W_pos = (const float*)d_in[4];
  const float* b_pos = (const float*)d_in[5];
  const float* W_qkv = (const float*)d_in[6];
  const float* b_qkv = (const float*)d_in[7];
  const float* W_out = (const float*)d_in[8];
  const float* b_out = (const float*)d_in[9];
  const float* scale = (const float*)d_in[10];
  float* outp = (float*)d_out;

  char* ws = (char*)d_ws;
  const size_t MB = 1 << 20;
  // region 0 (16MB): x_bf (dead after GEMM1) then hn
  bf16* x_bf   = (bf16*)(ws);
  bf16* hn     = (bf16*)(ws);
  bf16* wpos_t = (bf16*)(ws + 16 * MB);  // 2MB
  bf16* wqkv_t = (bf16*)(ws + 18 * MB);  // 5MB
  bf16* wout_t = (bf16*)(ws + 23 * MB);  // 1MB
  // region 24-32MB: pe_pj (2MB, dead after GEMM1), then vT (8MB)
  bf16* pe_pj  = (bf16*)(ws + 24 * MB);
  bf16* vT     = (bf16*)(ws + 24 * MB);
  // region 32-48MB: h (16MB, dead after featnorm), then attn_o (8MB)
  bf16* h      = (bf16*)(ws + 32 * MB);
  bf16* attn_o = (bf16*)(ws + 32 * MB);
  bf16* qkv    = (bf16*)(ws + 48 * MB);  // 40MB
  float* sqb   = (float*)(ws + 88 * MB);
  float* skb   = (float*)(ws + 88 * MB + 262144);

  conv_bf16_kernel<<<4096, 256, 0, stream>>>(x, x_bf);
  transpose_to_bf16<<<dim3(32, 32), 256, 0, stream>>>(W_pos, wpos_t, 1024, 1024);
  transpose_to_bf16<<<dim3(80, 32), 256, 0, stream>>>(W_qkv, wqkv_t, 1024, 2560);
  transpose_to_bf16<<<dim3(32, 16), 256, 0, stream>>>(W_out, wout_t, 512, 1024);
  pe_proj_kernel<<<4096, 256, 0, stream>>>(pe, W_pos, pe_pj);
  // h = x + x@W_pos + pe_pj + b_pos   (bf16 out)
  gemm_bf16<1><<<dim3(8, 64), 256, 0, stream>>>(x_bf, wpos_t, h, 8192, 1024, 1024,
                                                b_pos, x, pe_pj);
  featnorm_kernel<<<128, 512, 0, stream>>>(h, hn, gamma, beta);
  // qkv = hn @ W_qkv + b_qkv  (bf16 out)
  gemm_bf16<1><<<dim3(20, 64), 256, 0, stream>>>(hn, wqkv_t, qkv, 8192, 2560, 1024,
                                                 b_qkv, nullptr, nullptr);
  sqsk_kernel<<<8192, 256, 0, stream>>>(qkv, sqb, skb);
  vtrans_kernel<<<dim3(32, 16, 8), 256, 0, stream>>>(qkv, vT);
  attn_mfma<<<1024, 256, 0, stream>>>(qkv, vT, sqb, skb, scale, attn_o);
  // out = x + attn_o @ W_out + b_out  (fp32 out)
  gemm_bf16<0><<<dim3(8, 64), 256, 0, stream>>>(attn_o, wout_t, outp, 8192, 1024, 512,
                                                b_out, x, nullptr);
}